// Round 11
// baseline (122.642 us; speedup 1.0000x reference)
//
#include <hip/hip_runtime.h>
#include <hip/hip_bf16.h>

#define B_   4
#define LQ   512
#define LK   512
#define D_   128
#define H_   128
#define LKP  576        // padded EkT row stride (2304B); LKP/4 = 144 float4s
#define QS   4          // q-rows per fused block

#define TWO_LOG2E 2.885390081777927f   // 2*log2(e)
#define LOG2E     1.442695040888963f

__device__ __forceinline__ float fexp2(float x) {
#if __has_builtin(__builtin_amdgcn_exp2f)
  return __builtin_amdgcn_exp2f(x);     // v_exp_f32 (native exp2)
#else
  return exp2f(x);
#endif
}
__device__ __forceinline__ float frcp(float x) {
#if __has_builtin(__builtin_amdgcn_rcpf)
  return __builtin_amdgcn_rcpf(x);      // v_rcp_f32
#else
  return __fdividef(1.0f, x);
#endif
}

// one row x 4 k sigmoid-accumulations, 2 rcp per 4 elements (paired):
// d = 1 + eq*ek;  acc += w/d
__device__ __forceinline__ void sig4k(float eq, float w, float4 ek, float4& acc) {
  float d0 = fmaf(eq, ek.x, 1.f);
  float d1 = fmaf(eq, ek.y, 1.f);
  float d2 = fmaf(eq, ek.z, 1.f);
  float d3 = fmaf(eq, ek.w, 1.f);
  float R01 = frcp(d0 * d1);
  float R23 = frcp(d2 * d3);
  acc.x = fmaf(w * d1, R01, acc.x);
  acc.y = fmaf(w * d0, R01, acc.y);
  acc.z = fmaf(w * d3, R23, acc.z);
  acc.w = fmaf(w * d2, R23, acc.w);
}

// ---------------------------------------------------------------------------
// proj: 8 rows/block, 256 threads.
//   Eq  [row][h]  = exp2(2*log2e * q.Wq)
//   EkT [b][h][k] = exp2(2*log2e * k.Wk), transposed, stride LKP.
// exp2(q'+k') = Eq*Ek -> fused kernel needs NO exp in its hot loop.
// ---------------------------------------------------------------------------
__global__ __launch_bounds__(256) void proj_kernel(
    const float* __restrict__ queries, const float* __restrict__ keys,
    const float* __restrict__ Wq, const float* __restrict__ Wk,
    float* __restrict__ Eq, float* __restrict__ EkT) {
  __shared__ float s_x[8][D_];
  int r0 = blockIdx.x * 8;
  bool qside = r0 < B_ * LQ;
  const float* X = qside ? queries : keys;
  const float* W = qside ? Wq : Wk;
  int rb = qside ? r0 : r0 - B_ * LQ;
  int tid = threadIdx.x;
  for (int i = tid; i < 8 * D_; i += 256)
    s_x[i >> 7][i & 127] = X[(size_t)(rb + (i >> 7)) * D_ + (i & 127)];
  __syncthreads();
  int h = tid & 127, rh = tid >> 7;    // rows rh*4 .. rh*4+3
  const float4* x0 = (const float4*)s_x[rh * 4 + 0];
  const float4* x1 = (const float4*)s_x[rh * 4 + 1];
  const float4* x2 = (const float4*)s_x[rh * 4 + 2];
  const float4* x3 = (const float4*)s_x[rh * 4 + 3];
  float a0 = 0.f, a1 = 0.f, a2 = 0.f, a3 = 0.f;
  #pragma unroll 8
  for (int d4 = 0; d4 < D_ / 4; ++d4) {
    float4 xa = x0[d4], xb = x1[d4], xc = x2[d4], xd = x3[d4];  // ds_read_b128
    const float* Wd = W + 4 * d4 * H_ + h;
    float w0 = Wd[0], w1 = Wd[H_], w2 = Wd[2 * H_], w3 = Wd[3 * H_];  // coalesced
    a0 = fmaf(xa.x, w0, fmaf(xa.y, w1, fmaf(xa.z, w2, fmaf(xa.w, w3, a0))));
    a1 = fmaf(xb.x, w0, fmaf(xb.y, w1, fmaf(xb.z, w2, fmaf(xb.w, w3, a1))));
    a2 = fmaf(xc.x, w0, fmaf(xc.y, w1, fmaf(xc.z, w2, fmaf(xc.w, w3, a2))));
    a3 = fmaf(xd.x, w0, fmaf(xd.y, w1, fmaf(xd.z, w2, fmaf(xd.w, w3, a3))));
  }
  if (qside) {
    Eq[(size_t)(rb + rh * 4 + 0) * H_ + h] = fexp2(a0 * TWO_LOG2E);
    Eq[(size_t)(rb + rh * 4 + 1) * H_ + h] = fexp2(a1 * TWO_LOG2E);
    Eq[(size_t)(rb + rh * 4 + 2) * H_ + h] = fexp2(a2 * TWO_LOG2E);
    Eq[(size_t)(rb + rh * 4 + 3) * H_ + h] = fexp2(a3 * TWO_LOG2E);
  } else {
    int b = rb >> 9, kk = (rb & 511) + rh * 4;
    float* dst = EkT + ((size_t)b * H_ + h) * LKP + kk;
    dst[0] = fexp2(a0 * TWO_LOG2E);
    dst[1] = fexp2(a1 * TWO_LOG2E);
    dst[2] = fexp2(a2 * TWO_LOG2E);
    dst[3] = fexp2(a3 * TWO_LOG2E);
  }
}

// ---------------------------------------------------------------------------
// fused: block = (b = id&3, 4 q-rows). 256 thr = 4 waves. Grid 512 -> 2
// identical blocks/CU. Phase 1 is DENSE: all 512 k computed, NO vlen mask ->
// every wave/block/CU does identical work (the mask was capping VALUBusy at
// ~E[vlen]/512 = 50% for 5 rounds). vlen applies only in softmax (weight=0
// for k>=vlen -> output identical). Thread = (kq, rp): k-quad x row-pair,
// 8 indep accum chains, 8 elems per EkT float4 -> compute/load ~256cyc/4loads
// hides L2 latency via ILP alone.
// ---------------------------------------------------------------------------
__global__ __launch_bounds__(256) void fused_kernel(
    const float* __restrict__ Eq, const float* __restrict__ EkT,
    const float* __restrict__ values, const int* __restrict__ vlen_arr,
    const float* __restrict__ wv, const float* __restrict__ Wo,
    float* __restrict__ out) {
  int id = blockIdx.x;
  int b = id & 3, q0 = (id >> 2) * QS;
  int tid = threadIdx.x, wave = tid >> 6, lane = tid & 63;

  __shared__ float s_eq[QS][H_];      // 2 KB
  __shared__ float s_wv[H_];          // 0.5 KB
  __shared__ float s_sc[QS][LK];      // 8 KB  scores -> normalized weights
  __shared__ float s_po[4][QS][D_];   // 8 KB  [chunk][row][d] PV partials
  __shared__ float s_pr[QS][D_];      // 2 KB  reduced PV

  for (int i = tid; i < QS * H_; i += 256)
    s_eq[i >> 7][i & 127] = Eq[(size_t)(b * LQ + q0 + (i >> 7)) * H_ + (i & 127)];
  if (tid < H_) s_wv[tid] = wv[tid];
  __syncthreads();
  int vlen = vlen_arr[b];

  const float4* wv4p = (const float4*)s_wv;
  float sum_wv = 0.f;
  #pragma unroll
  for (int j = 0; j < H_ / 4; ++j) {
    float4 t4 = wv4p[j];
    sum_wv += t4.x + t4.y + t4.z + t4.w;
  }

  // ---- phase 1: DENSE scores. thread = (k-quad kq, row-pair rp). ----
  {
    int kq = tid & 127, rp = tid >> 7;         // rows 2rp, 2rp+1
    const float4* ekp = (const float4*)(EkT + (size_t)b * H_ * LKP);  // [h][144]
    const float4* qa4 = (const float4*)s_eq[2 * rp + 0];
    const float4* qb4 = (const float4*)s_eq[2 * rp + 1];
    float4 accA = {0.f, 0.f, 0.f, 0.f};
    float4 accB = {0.f, 0.f, 0.f, 0.f};
    #pragma unroll 2
    for (int h4 = 0; h4 < H_ / 4; ++h4) {
      float4 e0 = ekp[(size_t)(4 * h4 + 0) * (LKP / 4) + kq];  // 1KB/wave, L2-hot
      float4 e1 = ekp[(size_t)(4 * h4 + 1) * (LKP / 4) + kq];
      float4 e2 = ekp[(size_t)(4 * h4 + 2) * (LKP / 4) + kq];
      float4 e3 = ekp[(size_t)(4 * h4 + 3) * (LKP / 4) + kq];
      float4 w4 = wv4p[h4];                    // LDS broadcasts
      float4 qa = qa4[h4];
      float4 qb = qb4[h4];
      sig4k(qa.x, w4.x, e0, accA);  sig4k(qb.x, w4.x, e0, accB);
      sig4k(qa.y, w4.y, e1, accA);  sig4k(qb.y, w4.y, e1, accB);
      sig4k(qa.z, w4.z, e2, accA);  sig4k(qb.z, w4.z, e2, accB);
      sig4k(qa.w, w4.w, e3, accA);  sig4k(qb.w, w4.w, e3, accB);
    }
    float4 rA = { fmaf(-2.f, accA.x, sum_wv), fmaf(-2.f, accA.y, sum_wv),
                  fmaf(-2.f, accA.z, sum_wv), fmaf(-2.f, accA.w, sum_wv) };
    float4 rB = { fmaf(-2.f, accB.x, sum_wv), fmaf(-2.f, accB.y, sum_wv),
                  fmaf(-2.f, accB.z, sum_wv), fmaf(-2.f, accB.w, sum_wv) };
    ((float4*)s_sc[2 * rp + 0])[kq] = rA;      // stride-1 ds_write_b128
    ((float4*)s_sc[2 * rp + 1])[kq] = rB;      // (k>=vlen holds finite garbage)
  }
  __syncthreads();

  // ---- phase 2: masked softmax. wave w -> row w; vlen applied HERE. ----
  {
    float vals[LK / 64];
    float m = -3.0e38f;
    #pragma unroll
    for (int j = 0; j < LK / 64; ++j) {
      int k = lane + j * 64;
      float v = (k < vlen) ? s_sc[wave][k] : -1.0e30f;   // mask garbage
      vals[j] = v;
      m = fmaxf(m, v);
    }
    #pragma unroll
    for (int off = 32; off; off >>= 1) m = fmaxf(m, __shfl_xor(m, off));
    float sum = 0.f;
    #pragma unroll
    for (int j = 0; j < LK / 64; ++j) {
      float e = fexp2((vals[j] - m) * LOG2E);   // masked -> exp2(-huge) = 0
      vals[j] = e;
      sum += e;
    }
    #pragma unroll
    for (int off = 32; off; off >>= 1) sum += __shfl_xor(sum, off);
    float inv = frcp(sum);
    #pragma unroll
    for (int j = 0; j < LK / 64; ++j) s_sc[wave][lane + j * 64] = vals[j] * inv;
  }
  __syncthreads();

  // ---- phase 3: PV. wave w -> k-chunk [128w,128w+128) for ALL 4 rows. ----
  {
    int kbeg = wave * 128;
    int kend = min((vlen + 3) & ~3, kbeg + 128);     // weights are 0 past vlen
    const float4* v4 = (const float4*)(values + (size_t)b * LK * D_);  // [k][32]
    int dq = lane & 31, kpar = lane >> 5;            // d-quad, k-parity
    float4 a0 = {0,0,0,0}, a1 = {0,0,0,0}, a2 = {0,0,0,0}, a3 = {0,0,0,0};
    for (int kk = kbeg; kk < kend; kk += 4) {
      float4 va = v4[(size_t)(kk + 0 + kpar) * 32 + dq];   // 1KB/wave coalesced
      float4 vb = v4[(size_t)(kk + 2 + kpar) * 32 + dq];
      float4 w0 = *(const float4*)&s_sc[0][kk];            // LDS broadcasts
      float4 w1 = *(const float4*)&s_sc[1][kk];
      float4 w2 = *(const float4*)&s_sc[2][kk];
      float4 w3 = *(const float4*)&s_sc[3][kk];
      float wa0 = kpar ? w0.y : w0.x, wb0 = kpar ? w0.w : w0.z;  // cndmask selects
      float wa1 = kpar ? w1.y : w1.x, wb1 = kpar ? w1.w : w1.z;
      float wa2 = kpar ? w2.y : w2.x, wb2 = kpar ? w2.w : w2.z;
      float wa3 = kpar ? w3.y : w3.x, wb3 = kpar ? w3.w : w3.z;
      a0.x = fmaf(wa0, va.x, fmaf(wb0, vb.x, a0.x));
      a0.y = fmaf(wa0, va.y, fmaf(wb0, vb.y, a0.y));
      a0.z = fmaf(wa0, va.z, fmaf(wb0, vb.z, a0.z));
      a0.w = fmaf(wa0, va.w, fmaf(wb0, vb.w, a0.w));
      a1.x = fmaf(wa1, va.x, fmaf(wb1, vb.x, a1.x));
      a1.y = fmaf(wa1, va.y, fmaf(wb1, vb.y, a1.y));
      a1.z = fmaf(wa1, va.z, fmaf(wb1, vb.z, a1.z));
      a1.w = fmaf(wa1, va.w, fmaf(wb1, vb.w, a1.w));
      a2.x = fmaf(wa2, va.x, fmaf(wb2, vb.x, a2.x));
      a2.y = fmaf(wa2, va.y, fmaf(wb2, vb.y, a2.y));
      a2.z = fmaf(wa2, va.z, fmaf(wb2, vb.z, a2.z));
      a2.w = fmaf(wa2, va.w, fmaf(wb2, vb.w, a2.w));
      a3.x = fmaf(wa3, va.x, fmaf(wb3, vb.x, a3.x));
      a3.y = fmaf(wa3, va.y, fmaf(wb3, vb.y, a3.y));
      a3.z = fmaf(wa3, va.z, fmaf(wb3, vb.z, a3.z));
      a3.w = fmaf(wa3, va.w, fmaf(wb3, vb.w, a3.w));
    }
    // merge k-parity halves: lane l += lane l^32
    a0.x += __shfl_xor(a0.x, 32); a0.y += __shfl_xor(a0.y, 32);
    a0.z += __shfl_xor(a0.z, 32); a0.w += __shfl_xor(a0.w, 32);
    a1.x += __shfl_xor(a1.x, 32); a1.y += __shfl_xor(a1.y, 32);
    a1.z += __shfl_xor(a1.z, 32); a1.w += __shfl_xor(a1.w, 32);
    a2.x += __shfl_xor(a2.x, 32); a2.y += __shfl_xor(a2.y, 32);
    a2.z += __shfl_xor(a2.z, 32); a2.w += __shfl_xor(a2.w, 32);
    a3.x += __shfl_xor(a3.x, 32); a3.y += __shfl_xor(a3.y, 32);
    a3.z += __shfl_xor(a3.z, 32); a3.w += __shfl_xor(a3.w, 32);
    if (lane < 32) {
      ((float4*)s_po[wave][0])[dq] = a0;
      ((float4*)s_po[wave][1])[dq] = a1;
      ((float4*)s_po[wave][2])[dq] = a2;
      ((float4*)s_po[wave][3])[dq] = a3;
    }
  }
  __syncthreads();

  // ---- reduce chunk partials: 512 elems over 256 threads ----
  #pragma unroll
  for (int i = tid; i < QS * D_; i += 256) {
    int r = i >> 7, d = i & 127;
    s_pr[r][d] = s_po[0][r][d] + s_po[1][r][d] + s_po[2][r][d] + s_po[3][r][d];
  }
  __syncthreads();

  // ---- phase 4: Wo projection. thread -> col h, rows {r, r+2}. ----
  {
    int h = tid & 127, r = tid >> 7;
    float accA = 0.f, accB = 0.f;
    #pragma unroll 8
    for (int d = 0; d < D_; ++d) {
      float w = Wo[d * H_ + h];                  // coalesced, L2-hot
      accA = fmaf(s_pr[r][d], w, accA);          // LDS broadcasts
      accB = fmaf(s_pr[r + 2][d], w, accB);
    }
    out[(size_t)(b * LQ + q0 + r) * H_ + h] = accA;
    out[(size_t)(b * LQ + q0 + r + 2) * H_ + h] = accB;
  }
}

extern "C" void kernel_launch(void* const* d_in, const int* in_sizes, int n_in,
                              void* d_out, int out_size, void* d_ws, size_t ws_size,
                              hipStream_t stream) {
  const float* queries = (const float*)d_in[0];
  const float* keys    = (const float*)d_in[1];
  const float* values  = (const float*)d_in[2];
  const int*   vlen    = (const int*)d_in[3];
  const float* Wq      = (const float*)d_in[4];
  const float* Wk      = (const float*)d_in[5];
  const float* wv      = (const float*)d_in[6];
  const float* Wo      = (const float*)d_in[7];
  float* out = (float*)d_out;

  float* Eq  = (float*)d_ws;                            // 1.00 MB [row][h]
  float* EkT = Eq + (size_t)B_ * LQ * H_;               // 1.13 MB [b][h][k] stride LKP

  proj_kernel<<<dim3(B_ * (LQ + LK) / 8), 256, 0, stream>>>(queries, keys, Wq, Wk, Eq, EkT);
  fused_kernel<<<dim3(B_ * (LQ / QS)), 256, 0, stream>>>(Eq, EkT, values, vlen, wv, Wo, out);
}

// Round 13
// 114.086 us; speedup vs baseline: 1.0750x; 1.0750x over previous
//
#include <hip/hip_runtime.h>
#include <hip/hip_bf16.h>

#define B_   4
#define LQ   512
#define LK   512
#define D_   128
#define H_   128
#define LKP  576        // padded EkT row stride (2304B); LKP/4 = 144 float4s

#define TWO_LOG2E 2.885390081777927f   // 2*log2(e)
#define LOG2E     1.442695040888963f

__device__ __forceinline__ float fexp2(float x) {
#if __has_builtin(__builtin_amdgcn_exp2f)
  return __builtin_amdgcn_exp2f(x);     // v_exp_f32 (native exp2)
#else
  return exp2f(x);
#endif
}
__device__ __forceinline__ float frcp(float x) {
#if __has_builtin(__builtin_amdgcn_rcpf)
  return __builtin_amdgcn_rcpf(x);      // v_rcp_f32
#else
  return __fdividef(1.0f, x);
#endif
}

// one h x 4 k sigmoid-accumulations, 2 rcp per 4 elements (paired):
// d = 1 + eq*ek;  acc += w/d
__device__ __forceinline__ void sig4k(float eq, float w, float4 ek, float4& acc) {
  float d0 = fmaf(eq, ek.x, 1.f);
  float d1 = fmaf(eq, ek.y, 1.f);
  float d2 = fmaf(eq, ek.z, 1.f);
  float d3 = fmaf(eq, ek.w, 1.f);
  float R01 = frcp(d0 * d1);
  float R23 = frcp(d2 * d3);
  acc.x = fmaf(w * d1, R01, acc.x);
  acc.y = fmaf(w * d0, R01, acc.y);
  acc.z = fmaf(w * d3, R23, acc.z);
  acc.w = fmaf(w * d2, R23, acc.w);
}

// ---------------------------------------------------------------------------
// proj: 8 rows/block, 256 threads.
//   Eq  [row][h]  = exp2(2*log2e * q.Wq)
//   EkT [b][h][k] = exp2(2*log2e * k.Wk), transposed, stride LKP.
// ---------------------------------------------------------------------------
__global__ __launch_bounds__(256) void proj_kernel(
    const float* __restrict__ queries, const float* __restrict__ keys,
    const float* __restrict__ Wq, const float* __restrict__ Wk,
    float* __restrict__ Eq, float* __restrict__ EkT) {
  __shared__ float s_x[8][D_];
  int r0 = blockIdx.x * 8;
  bool qside = r0 < B_ * LQ;
  const float* X = qside ? queries : keys;
  const float* W = qside ? Wq : Wk;
  int rb = qside ? r0 : r0 - B_ * LQ;
  int tid = threadIdx.x;
  for (int i = tid; i < 8 * D_; i += 256)
    s_x[i >> 7][i & 127] = X[(size_t)(rb + (i >> 7)) * D_ + (i & 127)];
  __syncthreads();
  int h = tid & 127, rh = tid >> 7;    // rows rh*4 .. rh*4+3
  const float4* x0 = (const float4*)s_x[rh * 4 + 0];
  const float4* x1 = (const float4*)s_x[rh * 4 + 1];
  const float4* x2 = (const float4*)s_x[rh * 4 + 2];
  const float4* x3 = (const float4*)s_x[rh * 4 + 3];
  float a0 = 0.f, a1 = 0.f, a2 = 0.f, a3 = 0.f;
  #pragma unroll 8
  for (int d4 = 0; d4 < D_ / 4; ++d4) {
    float4 xa = x0[d4], xb = x1[d4], xc = x2[d4], xd = x3[d4];  // ds_read_b128
    const float* Wd = W + 4 * d4 * H_ + h;
    float w0 = Wd[0], w1 = Wd[H_], w2 = Wd[2 * H_], w3 = Wd[3 * H_];  // coalesced
    a0 = fmaf(xa.x, w0, fmaf(xa.y, w1, fmaf(xa.z, w2, fmaf(xa.w, w3, a0))));
    a1 = fmaf(xb.x, w0, fmaf(xb.y, w1, fmaf(xb.z, w2, fmaf(xb.w, w3, a1))));
    a2 = fmaf(xc.x, w0, fmaf(xc.y, w1, fmaf(xc.z, w2, fmaf(xc.w, w3, a2))));
    a3 = fmaf(xd.x, w0, fmaf(xd.y, w1, fmaf(xd.z, w2, fmaf(xd.w, w3, a3))));
  }
  if (qside) {
    Eq[(size_t)(rb + rh * 4 + 0) * H_ + h] = fexp2(a0 * TWO_LOG2E);
    Eq[(size_t)(rb + rh * 4 + 1) * H_ + h] = fexp2(a1 * TWO_LOG2E);
    Eq[(size_t)(rb + rh * 4 + 2) * H_ + h] = fexp2(a2 * TWO_LOG2E);
    Eq[(size_t)(rb + rh * 4 + 3) * H_ + h] = fexp2(a3 * TWO_LOG2E);
  } else {
    int b = rb >> 9, kk = (rb & 511) + rh * 4;
    float* dst = EkT + ((size_t)b * H_ + h) * LKP + kk;
    dst[0] = fexp2(a0 * TWO_LOG2E);
    dst[1] = fexp2(a1 * TWO_LOG2E);
    dst[2] = fexp2(a2 * TWO_LOG2E);
    dst[3] = fexp2(a3 * TWO_LOG2E);
  }
}

// ---------------------------------------------------------------------------
// score (DENSE, deep-grid): block = (b, kc of 128 k, qt of 4 rows). Grid 2048
// -> 8 blocks/CU, 32 waves/CU (8/SIMD). Thread = (k-quad, row, h-half):
// 256-elem chain; partial-h accs reduced via LDS. Writes RAW -2*acc
// (softmax shift-invariance: sum_wv dropped). vlen applied only in finish.
// ---------------------------------------------------------------------------
__global__ __launch_bounds__(256) void score_kernel(
    const float* __restrict__ Eq, const float* __restrict__ EkT,
    const float* __restrict__ wv, float* __restrict__ sc_g) {
  int id = blockIdx.x;
  int b = id & 3, kc = (id >> 2) & 3, qt = id >> 4;
  int q0 = qt * 4;
  int tid = threadIdx.x;

  __shared__ float s_eq[4][H_];        // 2 KB
  __shared__ float s_wv[H_];           // 0.5 KB
  __shared__ float s_red[2][4][128];   // 4 KB  [h-half][row][k] partials

  for (int i = tid; i < 4 * H_; i += 256)
    s_eq[i >> 7][i & 127] = Eq[(size_t)(b * LQ + q0 + (i >> 7)) * H_ + (i & 127)];
  if (tid < H_) s_wv[tid] = wv[tid];
  __syncthreads();

  int kq = tid & 31, row = (tid >> 5) & 3, hh = tid >> 7;
  const float4* ekp = (const float4*)(EkT + (size_t)b * H_ * LKP);  // [h][144]
  int c = kc * 32 + kq;                 // float4 column
  const float* eqr = s_eq[row];
  const float* wvp = s_wv;
  int hbase = hh * 64;
  float4 acc = {0.f, 0.f, 0.f, 0.f};
  #pragma unroll 4
  for (int h4 = 0; h4 < 16; ++h4) {
    int h = hbase + h4 * 4;
    float4 e0 = ekp[(size_t)(h + 0) * 144 + c];   // 512B/wave, L2-hot
    float4 e1 = ekp[(size_t)(h + 1) * 144 + c];
    float4 e2 = ekp[(size_t)(h + 2) * 144 + c];
    float4 e3 = ekp[(size_t)(h + 3) * 144 + c];
    sig4k(eqr[h + 0], wvp[h + 0], e0, acc);       // LDS broadcasts
    sig4k(eqr[h + 1], wvp[h + 1], e1, acc);
    sig4k(eqr[h + 2], wvp[h + 2], e2, acc);
    sig4k(eqr[h + 3], wvp[h + 3], e3, acc);
  }
  ((float4*)s_red[hh][row])[kq] = acc;            // stride-1 ds_write_b128
  __syncthreads();
  if (tid < 128) {
    int r2 = tid >> 5, k2 = tid & 31;
    float4 a = ((const float4*)s_red[0][r2])[k2];
    float4 b4 = ((const float4*)s_red[1][r2])[k2];
    float4 r4 = { -2.f * (a.x + b4.x), -2.f * (a.y + b4.y),
                  -2.f * (a.z + b4.z), -2.f * (a.w + b4.w) };
    ((float4*)(sc_g + (size_t)(b * LQ + q0 + r2) * LK + kc * 128))[k2] = r4;
  }
}

// ---------------------------------------------------------------------------
// finish: block = (b = id&3, 4 q-rows), 256 thr = 4 waves. Grid 512.
// softmax: wave w -> row w (float4 loads, vlen masked HERE). PV: wave w ->
// k-chunk w for ALL 4 rows (V read once/block). Then Wo projection.
// ---------------------------------------------------------------------------
__global__ __launch_bounds__(256) void finish_kernel(
    const float* __restrict__ sc_g, const float* __restrict__ values,
    const int* __restrict__ vlen_arr, const float* __restrict__ Wo,
    float* __restrict__ out) {
  int id = blockIdx.x;
  int b = id & 3, q0 = (id >> 2) * 4;
  int tid = threadIdx.x, wave = tid >> 6, lane = tid & 63;
  int vlen = vlen_arr[b];

  __shared__ float s_w[4][LK];        // 8 KB normalized weights (0 for k>=vlen)
  __shared__ float s_po[4][4][D_];    // 8 KB [chunk][row][d] PV partials
  __shared__ float s_pr[4][D_];       // 2 KB reduced PV

  // ---- softmax: wave w -> row q0+w; float4 loads; mask garbage to -1e30 ----
  {
    const float4* srow4 = (const float4*)(sc_g + (size_t)(b * LQ + q0 + wave) * LK);
    float4 v0 = srow4[lane];          // k = 4*lane + e
    float4 v1 = srow4[lane + 64];     // k = 256 + 4*lane + e
    int k0 = 4 * lane, k1 = 256 + 4 * lane;
    v0.x = (k0 + 0 < vlen) ? v0.x : -1.0e30f;
    v0.y = (k0 + 1 < vlen) ? v0.y : -1.0e30f;
    v0.z = (k0 + 2 < vlen) ? v0.z : -1.0e30f;
    v0.w = (k0 + 3 < vlen) ? v0.w : -1.0e30f;
    v1.x = (k1 + 0 < vlen) ? v1.x : -1.0e30f;
    v1.y = (k1 + 1 < vlen) ? v1.y : -1.0e30f;
    v1.z = (k1 + 2 < vlen) ? v1.z : -1.0e30f;
    v1.w = (k1 + 3 < vlen) ? v1.w : -1.0e30f;
    float m = fmaxf(fmaxf(fmaxf(v0.x, v0.y), fmaxf(v0.z, v0.w)),
                    fmaxf(fmaxf(v1.x, v1.y), fmaxf(v1.z, v1.w)));
    #pragma unroll
    for (int off = 32; off; off >>= 1) m = fmaxf(m, __shfl_xor(m, off));
    float4 e0, e1;
    e0.x = fexp2((v0.x - m) * LOG2E);  e0.y = fexp2((v0.y - m) * LOG2E);
    e0.z = fexp2((v0.z - m) * LOG2E);  e0.w = fexp2((v0.w - m) * LOG2E);
    e1.x = fexp2((v1.x - m) * LOG2E);  e1.y = fexp2((v1.y - m) * LOG2E);
    e1.z = fexp2((v1.z - m) * LOG2E);  e1.w = fexp2((v1.w - m) * LOG2E);
    float sum = e0.x + e0.y + e0.z + e0.w + e1.x + e1.y + e1.z + e1.w;
    #pragma unroll
    for (int off = 32; off; off >>= 1) sum += __shfl_xor(sum, off);
    float inv = frcp(sum);
    e0.x *= inv; e0.y *= inv; e0.z *= inv; e0.w *= inv;
    e1.x *= inv; e1.y *= inv; e1.z *= inv; e1.w *= inv;
    ((float4*)s_w[wave])[lane]      = e0;   // stride-1 ds_write_b128
    ((float4*)s_w[wave])[lane + 64] = e1;
  }
  __syncthreads();

  // ---- PV: wave w -> k-chunk [128w,128w+128) for ALL 4 rows ----
  {
    int kbeg = wave * 128;
    int kend = min((vlen + 3) & ~3, kbeg + 128);     // weights are 0 past vlen
    const float4* v4 = (const float4*)(values + (size_t)b * LK * D_);  // [k][32]
    int dq = lane & 31, kpar = lane >> 5;            // d-quad, k-parity
    float4 a0 = {0,0,0,0}, a1 = {0,0,0,0}, a2 = {0,0,0,0}, a3 = {0,0,0,0};
    for (int kk = kbeg; kk < kend; kk += 4) {
      float4 va = v4[(size_t)(kk + 0 + kpar) * 32 + dq];   // 1KB/wave coalesced
      float4 vb = v4[(size_t)(kk + 2 + kpar) * 32 + dq];
      float4 w0 = *(const float4*)&s_w[0][kk];             // LDS broadcasts
      float4 w1 = *(const float4*)&s_w[1][kk];
      float4 w2 = *(const float4*)&s_w[2][kk];
      float4 w3 = *(const float4*)&s_w[3][kk];
      float wa0 = kpar ? w0.y : w0.x, wb0 = kpar ? w0.w : w0.z;  // cndmask selects
      float wa1 = kpar ? w1.y : w1.x, wb1 = kpar ? w1.w : w1.z;
      float wa2 = kpar ? w2.y : w2.x, wb2 = kpar ? w2.w : w2.z;
      float wa3 = kpar ? w3.y : w3.x, wb3 = kpar ? w3.w : w3.z;
      a0.x = fmaf(wa0, va.x, fmaf(wb0, vb.x, a0.x));
      a0.y = fmaf(wa0, va.y, fmaf(wb0, vb.y, a0.y));
      a0.z = fmaf(wa0, va.z, fmaf(wb0, vb.z, a0.z));
      a0.w = fmaf(wa0, va.w, fmaf(wb0, vb.w, a0.w));
      a1.x = fmaf(wa1, va.x, fmaf(wb1, vb.x, a1.x));
      a1.y = fmaf(wa1, va.y, fmaf(wb1, vb.y, a1.y));
      a1.z = fmaf(wa1, va.z, fmaf(wb1, vb.z, a1.z));
      a1.w = fmaf(wa1, va.w, fmaf(wb1, vb.w, a1.w));
      a2.x = fmaf(wa2, va.x, fmaf(wb2, vb.x, a2.x));
      a2.y = fmaf(wa2, va.y, fmaf(wb2, vb.y, a2.y));
      a2.z = fmaf(wa2, va.z, fmaf(wb2, vb.z, a2.z));
      a2.w = fmaf(wa2, va.w, fmaf(wb2, vb.w, a2.w));
      a3.x = fmaf(wa3, va.x, fmaf(wb3, vb.x, a3.x));
      a3.y = fmaf(wa3, va.y, fmaf(wb3, vb.y, a3.y));
      a3.z = fmaf(wa3, va.z, fmaf(wb3, vb.z, a3.z));
      a3.w = fmaf(wa3, va.w, fmaf(wb3, vb.w, a3.w));
    }
    a0.x += __shfl_xor(a0.x, 32); a0.y += __shfl_xor(a0.y, 32);
    a0.z += __shfl_xor(a0.z, 32); a0.w += __shfl_xor(a0.w, 32);
    a1.x += __shfl_xor(a1.x, 32); a1.y += __shfl_xor(a1.y, 32);
    a1.z += __shfl_xor(a1.z, 32); a1.w += __shfl_xor(a1.w, 32);
    a2.x += __shfl_xor(a2.x, 32); a2.y += __shfl_xor(a2.y, 32);
    a2.z += __shfl_xor(a2.z, 32); a2.w += __shfl_xor(a2.w, 32);
    a3.x += __shfl_xor(a3.x, 32); a3.y += __shfl_xor(a3.y, 32);
    a3.z += __shfl_xor(a3.z, 32); a3.w += __shfl_xor(a3.w, 32);
    if (lane < 32) {
      ((float4*)s_po[wave][0])[dq] = a0;
      ((float4*)s_po[wave][1])[dq] = a1;
      ((float4*)s_po[wave][2])[dq] = a2;
      ((float4*)s_po[wave][3])[dq] = a3;
    }
  }
  __syncthreads();

  // ---- reduce chunk partials ----
  #pragma unroll
  for (int i = tid; i < 4 * D_; i += 256) {
    int r = i >> 7, d = i & 127;
    s_pr[r][d] = s_po[0][r][d] + s_po[1][r][d] + s_po[2][r][d] + s_po[3][r][d];
  }
  __syncthreads();

  // ---- Wo projection: thread -> col h, rows {r, r+2} ----
  {
    int h = tid & 127, r = tid >> 7;
    float accA = 0.f, accB = 0.f;
    #pragma unroll 8
    for (int d = 0; d < D_; ++d) {
      float w = Wo[d * H_ + h];                  // coalesced, L2-hot
      accA = fmaf(s_pr[r][d], w, accA);          // LDS broadcasts
      accB = fmaf(s_pr[r + 2][d], w, accB);
    }
    out[(size_t)(b * LQ + q0 + r) * H_ + h] = accA;
    out[(size_t)(b * LQ + q0 + r + 2) * H_ + h] = accB;
  }
}

extern "C" void kernel_launch(void* const* d_in, const int* in_sizes, int n_in,
                              void* d_out, int out_size, void* d_ws, size_t ws_size,
                              hipStream_t stream) {
  const float* queries = (const float*)d_in[0];
  const float* keys    = (const float*)d_in[1];
  const float* values  = (const float*)d_in[2];
  const int*   vlen    = (const int*)d_in[3];
  const float* Wq      = (const float*)d_in[4];
  const float* Wk      = (const float*)d_in[5];
  const float* wv      = (const float*)d_in[6];
  const float* Wo      = (const float*)d_in[7];
  float* out = (float*)d_out;

  float* Eq   = (float*)d_ws;                           // 1.00 MB [row][h]
  float* EkT  = Eq + (size_t)B_ * LQ * H_;              // 1.13 MB [b][h][k] stride LKP
  float* sc_g = EkT + (size_t)B_ * H_ * LKP;            // 4.00 MB [b][q][k]

  proj_kernel<<<dim3(B_ * (LQ + LK) / 8), 256, 0, stream>>>(queries, keys, Wq, Wk, Eq, EkT);
  score_kernel<<<dim3(2048), 256, 0, stream>>>(Eq, EkT, wv, sc_g);
  finish_kernel<<<dim3(512), 256, 0, stream>>>(sc_g, values, vlen, Wo, out);
}